// Round 9
// baseline (78.767 us; speedup 1.0000x reference)
//
#include <hip/hip_runtime.h>
#include <math.h>

#define BSZ 4
#define NN  256
#define CC  96
#define TT  16                 // tile side
#define NTILES 136             // 16*17/2 triangular tiles per batch
#define RSTR 100               // LDS row stride (floats): 16B-aligned, 2-way banks free
#define ARR  (TT * RSTR)       // 1600 floats per array

#define XIN_OFF  0
#define EH_OFF   2048          // BSZ*NN*2
#define COV_OFF  100352        // 2048 + BSZ*NN*CC

#define INV_SQRT_2PI 0.3989422804014327f
#define EXP2C       -0.7213475204444817f   // -0.5*log2(e)
#define KL2E        -2.4554670f            // -1.702*log2(e)  (sigmoid-Phi)
// Abramowitz-Stegun 7.1.25 (3-term), arg pre-scaled by 1/sqrt2 (folded into
// P), 0.5 folded into the coefficients. Phi abs err ~1.3e-5. Used in the
// row/Eh/dvals phases only (cheap there, feeds Eh output directly).
#define PHI_P   0.33267253f
#define PHI_C1  0.1740121f
#define PHI_C2 -0.0479399f
#define PHI_C3  0.3739278f

__device__ __forceinline__ float phi_from_exp_s(float u, float e) {
    float t  = __builtin_amdgcn_rcpf(__builtin_fmaf(PHI_P, fabsf(u), 1.0f));
    float hp = __builtin_fmaf(__builtin_fmaf(PHI_C3, t, PHI_C2), t, PHI_C1) * t * e;
    return 0.5f + __builtin_copysignf(0.5f - hp, u);
}

__device__ __forceinline__ int tri_offset(int k) {   // tiles before row k
    return k * TT - (k * (k - 1)) / 2;
}
__device__ __forceinline__ void tri_decode(int t, int& ti, int& tj) {
    float disc = 1089.0f - 8.0f * (float)t;          // (2T+1)^2 - 8t, T=16
    ti = (int)((33.0f - __builtin_amdgcn_sqrtf(disc)) * 0.5f);
    while (tri_offset(ti + 1) <= t) ++ti;            // float-precision fixup
    while (tri_offset(ti) > t) --ti;
    tj = ti + (t - tri_offset(ti));
}

// Single fused kernel (R8 structure; pair loop switched to sigmoid-Phi).
__global__ __launch_bounds__(512) void relu_cov_fused(
    const float* __restrict__ xin, const float* __restrict__ meanin,
    const float* __restrict__ kin, float* __restrict__ out)
{
    const int blk = blockIdx.x;     // b*NTILES + t
    const int b   = blk / NTILES;
    const int t   = blk - b * NTILES;
    const int tid = threadIdx.x;

    int ti, tj;
    tri_decode(t, ti, tj);
    const bool diag = (ti == tj);

    __shared__ __align__(16) float lds[4 * ARR];   // [smi | sEi | smj | sEj]
    __shared__ float red[512];
    __shared__ float srowS[32], srowR[32], srowV[32];
    float* const smi = lds;
    float* const sEi = lds + ARR;
    float* const smj = lds + 2 * ARR;
    float* const sEj = lds + 3 * ARR;

    // --- Phase 1: row consts + stage meanin ---
    if (tid < 32) {
        int row = (tid < 16) ? (ti * TT + tid) : (tj * TT + (tid - 16));
        float kd  = kin[((size_t)(b * NN + row)) * NN + row] + 1e-6f;
        float var = fmaxf(kd, 1e-8f);
        float st  = __builtin_amdgcn_sqrtf(var);
        srowV[tid] = var;
        srowS[tid] = st;
        srowR[tid] = __builtin_amdgcn_rcpf(st);
    }
#pragma unroll
    for (int it = 0; it < 2; ++it) {
        int k = tid + it * 512;         // 2 arrays x 16 rows x 24 float4 = 768
        if (k < 768) {
            int arr = k / 384;          // 0 = i-rows, 1 = j-rows
            int rem = k - arr * 384;
            int r   = rem / 24;
            int q   = rem - r * 24;
            int row = ((arr == 0) ? ti : tj) * TT + r;
            float4 v = *((const float4*)(meanin + ((size_t)(b * NN + row)) * CC) + q);
            *(float4*)(lds + arr * 2 * ARR + r * RSTR + q * 4) = v;
        }
    }
    __syncthreads();

    // --- Phase 2: Eh for 32 rows (2 arrays x 16 x 96 = 3072, 6/thread) ---
#pragma unroll
    for (int it = 0; it < 6; ++it) {
        int k   = tid + it * 512;
        int arr = k / 1536;
        int rem = k - arr * 1536;
        int r   = rem / 96;
        int c   = rem - r * 96;
        float m  = lds[arr * 2 * ARR + r * RSTR + c];
        float st = srowS[arr * 16 + r];
        float rs = srowR[arr * 16 + r];
        float z  = m * rs;
        float e  = __builtin_amdgcn_exp2f(z * z * EXP2C);
        float Ph = phi_from_exp_s(z, e);
        float Eh = __builtin_fmaf(m, Ph, st * (INV_SQRT_2PI * e));
        lds[(arr * 2 + 1) * ARR + r * RSTR + c] = Eh;
    }
    __syncthreads();

    // --- Phase 2b: diagonal-tile global outputs ---
    if (diag) {
#pragma unroll
        for (int it = 0; it < 3; ++it) {         // Eh output: 16 x 96
            int k = tid + it * 512;
            int r = k / 96, c = k - r * 96;
            out[EH_OFF + ((size_t)(b * NN + ti * TT + r)) * CC + c] = sEi[r * RSTR + c];
        }
        if (tid < 32) {                          // xin copy: 16 rows x 2
            int r = tid >> 1, d = tid & 1;
            size_t o = ((size_t)(b * NN + ti * TT + r)) * 2 + d;
            out[XIN_OFF + o] = xin[o];
        }
        {                                        // dvals: tid = r*32 + s, 3 c each
            int r = tid >> 5, s = tid & 31;
            float st = srowS[r], var = srowV[r], rs = srowR[r];
            float dsum = 0.0f;
#pragma unroll
            for (int dc = 0; dc < 3; ++dc) {
                int c = s * 3 + dc;
                float m  = smi[r * RSTR + c];
                float Eh = sEi[r * RSTR + c];
                float z  = m * rs;
                float e  = __builtin_amdgcn_exp2f(z * z * EXP2C);
                float Ph = phi_from_exp_s(z, e);
                float ph = INV_SQRT_2PI * e;
                float dt = __builtin_fmaf(__builtin_fmaf(m, m, var), Ph,
                           __builtin_fmaf(m * st, ph, -Eh * Eh));
                dsum += dt;
            }
            dsum += __shfl_down(dsum, 16, 32);
            dsum += __shfl_down(dsum,  8, 32);
            dsum += __shfl_down(dsum,  4, 32);
            dsum += __shfl_down(dsum,  2, 32);
            dsum += __shfl_down(dsum,  1, 32);
            if (s == 0) {
                float dval = fmaxf(dsum * (1.0f / 96.0f), 1e-6f);
                int row = ti * TT + r;
                out[COV_OFF + ((size_t)(b * NN + row)) * NN + row] = dval + 1e-6f;
            }
        }
    }

    // --- Phase 3: pair loop (sigmoid-Phi) ---
    const int p     = tid & 255;
    const int h     = tid >> 8;        // c-half 0/1
    const int i_loc = p >> 4;
    const int j_loc = p & 15;
    const int i = ti * TT + i_loc;
    const int j = tj * TT + j_loc;

    const float m00 = srowV[i_loc];         // == kdiag_i + 1e-6 (clip non-binding)
    const float m11 = srowV[16 + j_loc];
    const float m01 = kin[((size_t)(b * NN + i)) * NN + j];   // == m10 (symmetric)

    const float det = __builtin_fmaf(-m01, m01, m00 * m11);
    const float s   = __builtin_amdgcn_sqrtf(fmaxf(det, 1e-8f));
    const float tt  = fmaxf(__builtin_amdgcn_sqrtf(m00 + m11 + 2.0f * s), 1e-8f);
    const float rt  = __builtin_amdgcn_rcpf(tt);
    const float s00 = (m00 + s) * rt;
    const float s01 = m01 * rt;
    const float s11 = (m11 + s) * rt;
    const float dS  = fmaxf(__builtin_fmaf(-s01, s01, s00 * s11), 1e-8f);
    const float rdS = __builtin_amdgcn_rcpf(dS);
    const float i00 = s11 * rdS;
    const float i01 = -s01 * rdS;
    const float i11 = s00 * rdS;
    // psi brackets collapse; INV_SQRT_2PI folded in (see R4/R5 derivation).
    const float qd = -INV_SQRT_2PI * s01 * s01 * s01 * rdS;
    const float qj =  INV_SQRT_2PI * s00 * s00 * s11 * rdS;
    const float qi =  INV_SQRT_2PI * s00 * s11 * s11 * rdS;
    const float c2 = 2.0f * INV_SQRT_2PI * INV_SQRT_2PI * s01 * s01;

    const float* Lmi = smi + i_loc * RSTR + h * 48;
    const float* LEi = sEi + i_loc * RSTR + h * 48;
    const float* Lmj = smj + j_loc * RSTR + h * 48;
    const float* LEj = sEj + j_loc * RSTR + h * 48;

    float acc0 = 0.0f, acc1 = 0.0f, acc2 = 0.0f, acc3 = 0.0f;

    auto elem = [&](float mi, float mjv, float Ei, float Ej, float& acc) {
        float u1 = __builtin_fmaf(i01, mjv, i00 * mi);
        float u2 = __builtin_fmaf(i11, mjv, i01 * mi);
        float e1 = __builtin_amdgcn_exp2f(u1 * u1 * EXP2C);
        float e2 = __builtin_amdgcn_exp2f(u2 * u2 * EXP2C);
        // Phi ~ sigmoid(1.702u); clamp u >= -15 so exp2 <= 2^36.8 (no inf in
        // the shared-rcp product; sigma(-25.5) ~ 8e-12 — no accuracy loss).
        float g1 = __builtin_amdgcn_exp2f(fmaxf(u1, -15.0f) * KL2E);
        float g2 = __builtin_amdgcn_exp2f(fmaxf(u2, -15.0f) * KL2E);
        float den1 = 1.0f + g1;
        float den2 = 1.0f + g2;
        float rp   = __builtin_amdgcn_rcpf(den1 * den2);   // one rcp, both Phi's
        float Phi1 = den2 * rp;
        float Phi2 = den1 * rp;
        float a  = __builtin_fmaf(mi, mjv, m01);
        float bb = __builtin_fmaf(qd, mi, qj * mjv);
        float cc = __builtin_fmaf(qi, mi, qd * mjv);
        // Phi2*(a*Phi1 + bb*e1) + e2*(cc*Phi1 + c2*e1) - Ei*Ej
        float ta = __builtin_fmaf(a,  Phi1, bb * e1);
        float tb = __builtin_fmaf(cc, Phi1, c2 * e1);
        acc = __builtin_fmaf(Phi2, ta, acc);
        acc = __builtin_fmaf(e2,   tb, acc);
        acc = __builtin_fmaf(-Ei,  Ej, acc);
    };

#pragma unroll 4
    for (int q = 0; q < 12; ++q) {
        float4 mi4 = *(const float4*)(Lmi + q * 4);
        float4 mj4 = *(const float4*)(Lmj + q * 4);
        float4 Ei4 = *(const float4*)(LEi + q * 4);
        float4 Ej4 = *(const float4*)(LEj + q * 4);
        elem(mi4.x, mj4.x, Ei4.x, Ej4.x, acc0);
        elem(mi4.y, mj4.y, Ei4.y, Ej4.y, acc1);
        elem(mi4.z, mj4.z, Ei4.z, Ej4.z, acc2);
        elem(mi4.w, mj4.w, Ei4.w, Ej4.w, acc3);
    }

    red[tid] = (acc0 + acc1) + (acc2 + acc3);
    __syncthreads();

    if (tid < 256 && i < j) {
        float v = (red[tid] + red[tid + 256]) * (1.0f / 96.0f);
        out[COV_OFF + ((size_t)(b * NN + i)) * NN + j] = v;
        out[COV_OFF + ((size_t)(b * NN + j)) * NN + i] = v;
    }
}

extern "C" void kernel_launch(void* const* d_in, const int* in_sizes, int n_in,
                              void* d_out, int out_size, void* d_ws, size_t ws_size,
                              hipStream_t stream) {
    const float* xin    = (const float*)d_in[0];
    const float* meanin = (const float*)d_in[1];
    const float* kin    = (const float*)d_in[2];
    float* out = (float*)d_out;

    relu_cov_fused<<<BSZ * NTILES, 512, 0, stream>>>(xin, meanin, kin, out);
}

// Round 10
// 76.902 us; speedup vs baseline: 1.0243x; 1.0243x over previous
//
#include <hip/hip_runtime.h>
#include <math.h>

#define BSZ 4
#define NN  256
#define CC  96
#define TT  16                 // tile side
#define NTILES 136             // 16*17/2 triangular tiles per batch
#define RSTR 100               // LDS row stride (floats): 16B-aligned, 2-way banks free
#define ARR  (TT * RSTR)       // 1600 floats per array

#define XIN_OFF  0
#define EH_OFF   2048          // BSZ*NN*2
#define COV_OFF  100352        // 2048 + BSZ*NN*CC

#define INV_SQRT_2PI 0.3989422804014327f
#define EXP2C       -0.7213475204444817f   // -0.5*log2(e)
// Abramowitz-Stegun 7.1.25 (3-term), arg pre-scaled by 1/sqrt2 (folded into
// P), 0.5 folded into the coefficients. Phi abs err ~1.3e-5.
#define PHI_P   0.33267253f
#define PHI_C1  0.1740121f
#define PHI_C2 -0.0479399f
#define PHI_C3  0.3739278f

__device__ __forceinline__ float phi_from_exp_s(float u, float e) {
    float t  = __builtin_amdgcn_rcpf(__builtin_fmaf(PHI_P, fabsf(u), 1.0f));
    float hp = __builtin_fmaf(__builtin_fmaf(PHI_C3, t, PHI_C2), t, PHI_C1) * t * e;
    return 0.5f + __builtin_copysignf(0.5f - hp, u);
}

__device__ __forceinline__ int tri_offset(int k) {   // tiles before row k
    return k * TT - (k * (k - 1)) / 2;
}
__device__ __forceinline__ void tri_decode(int t, int& ti, int& tj) {
    float disc = 1089.0f - 8.0f * (float)t;          // (2T+1)^2 - 8t, T=16
    ti = (int)((33.0f - __builtin_amdgcn_sqrtf(disc)) * 0.5f);
    while (tri_offset(ti + 1) <= t) ++ti;            // float-precision fixup
    while (tri_offset(ti) > t) --ti;
    tj = ti + (t - tri_offset(ti));
}

// Single fused kernel. Pair phase: 2x2 pair sub-tile per thread
// (64 pair-threads x 8 c-chunks of 12), A&S Phi, 8-chunk LDS reduction.
__global__ __launch_bounds__(512) void relu_cov_fused(
    const float* __restrict__ xin, const float* __restrict__ meanin,
    const float* __restrict__ kin, float* __restrict__ out)
{
    const int blk = blockIdx.x;     // b*NTILES + t
    const int b   = blk / NTILES;
    const int t   = blk - b * NTILES;
    const int tid = threadIdx.x;

    int ti, tj;
    tri_decode(t, ti, tj);
    const bool diag = (ti == tj);

    __shared__ __align__(16) float lds[4 * ARR];   // [smi | sEi | smj | sEj]
    __shared__ float red[8 * 256];                 // [chunk][pair]
    __shared__ float srowS[32], srowR[32], srowV[32];
    float* const smi = lds;
    float* const sEi = lds + ARR;
    float* const smj = lds + 2 * ARR;
    float* const sEj = lds + 3 * ARR;

    // --- Phase 1: row consts + stage meanin ---
    if (tid < 32) {
        int row = (tid < 16) ? (ti * TT + tid) : (tj * TT + (tid - 16));
        float kd  = kin[((size_t)(b * NN + row)) * NN + row] + 1e-6f;
        float var = fmaxf(kd, 1e-8f);
        float st  = __builtin_amdgcn_sqrtf(var);
        srowV[tid] = var;
        srowS[tid] = st;
        srowR[tid] = __builtin_amdgcn_rcpf(st);
    }
#pragma unroll
    for (int it = 0; it < 2; ++it) {
        int k = tid + it * 512;         // 2 arrays x 16 rows x 24 float4 = 768
        if (k < 768) {
            int arr = k / 384;          // 0 = i-rows, 1 = j-rows
            int rem = k - arr * 384;
            int r   = rem / 24;
            int q   = rem - r * 24;
            int row = ((arr == 0) ? ti : tj) * TT + r;
            float4 v = *((const float4*)(meanin + ((size_t)(b * NN + row)) * CC) + q);
            *(float4*)(lds + arr * 2 * ARR + r * RSTR + q * 4) = v;
        }
    }
    __syncthreads();

    // --- Phase 2: Eh for 32 rows (2 arrays x 16 x 96 = 3072, 6/thread) ---
#pragma unroll
    for (int it = 0; it < 6; ++it) {
        int k   = tid + it * 512;
        int arr = k / 1536;
        int rem = k - arr * 1536;
        int r   = rem / 96;
        int c   = rem - r * 96;
        float m  = lds[arr * 2 * ARR + r * RSTR + c];
        float st = srowS[arr * 16 + r];
        float rs = srowR[arr * 16 + r];
        float z  = m * rs;
        float e  = __builtin_amdgcn_exp2f(z * z * EXP2C);
        float Ph = phi_from_exp_s(z, e);
        float Eh = __builtin_fmaf(m, Ph, st * (INV_SQRT_2PI * e));
        lds[(arr * 2 + 1) * ARR + r * RSTR + c] = Eh;
    }
    __syncthreads();

    // --- Phase 2b: diagonal-tile global outputs ---
    if (diag) {
#pragma unroll
        for (int it = 0; it < 3; ++it) {         // Eh output: 16 x 96
            int k = tid + it * 512;
            int r = k / 96, c = k - r * 96;
            out[EH_OFF + ((size_t)(b * NN + ti * TT + r)) * CC + c] = sEi[r * RSTR + c];
        }
        if (tid < 32) {                          // xin copy: 16 rows x 2
            int r = tid >> 1, d = tid & 1;
            size_t o = ((size_t)(b * NN + ti * TT + r)) * 2 + d;
            out[XIN_OFF + o] = xin[o];
        }
        {                                        // dvals: tid = r*32 + s, 3 c each
            int r = tid >> 5, s = tid & 31;
            float st = srowS[r], var = srowV[r], rs = srowR[r];
            float dsum = 0.0f;
#pragma unroll
            for (int dc = 0; dc < 3; ++dc) {
                int c = s * 3 + dc;
                float m  = smi[r * RSTR + c];
                float Eh = sEi[r * RSTR + c];
                float z  = m * rs;
                float e  = __builtin_amdgcn_exp2f(z * z * EXP2C);
                float Ph = phi_from_exp_s(z, e);
                float ph = INV_SQRT_2PI * e;
                float dt = __builtin_fmaf(__builtin_fmaf(m, m, var), Ph,
                           __builtin_fmaf(m * st, ph, -Eh * Eh));
                dsum += dt;
            }
            dsum += __shfl_down(dsum, 16, 32);
            dsum += __shfl_down(dsum,  8, 32);
            dsum += __shfl_down(dsum,  4, 32);
            dsum += __shfl_down(dsum,  2, 32);
            dsum += __shfl_down(dsum,  1, 32);
            if (s == 0) {
                float dval = fmaxf(dsum * (1.0f / 96.0f), 1e-6f);
                int row = ti * TT + r;
                out[COV_OFF + ((size_t)(b * NN + row)) * NN + row] = dval + 1e-6f;
            }
        }
    }

    // --- Phase 3: pair loop, 2x2 pairs per thread ---
    const int pt = tid & 63;        // pair-thread
    const int ch = tid >> 6;        // c-chunk 0..7 (12 c each)
    const int ia = (pt >> 3) * 2;   // i_loc base (0,2,..,14)
    const int jb = (pt & 7) * 2;    // j_loc base
    const int c0 = ch * 12;

    // per-pair constants [ii][jj]
    float Ci00[2][2], Ci01[2][2], Ci11[2][2], Cm01[2][2];
    float Cqd[2][2], Cqj[2][2], Cqi[2][2], Cc2[2][2];
    {
        const float* kb = kin + (size_t)b * NN * NN;
#pragma unroll
        for (int ii = 0; ii < 2; ++ii) {
            const int gi = ti * TT + ia + ii;
            const float m00 = srowV[ia + ii];
            float2 k2 = *(const float2*)(kb + (size_t)gi * NN + tj * TT + jb);
#pragma unroll
            for (int jj = 0; jj < 2; ++jj) {
                const float m11 = srowV[16 + jb + jj];
                const float m01 = (jj == 0) ? k2.x : k2.y;
                const float det = __builtin_fmaf(-m01, m01, m00 * m11);
                const float s   = __builtin_amdgcn_sqrtf(fmaxf(det, 1e-8f));
                const float tt  = fmaxf(__builtin_amdgcn_sqrtf(m00 + m11 + 2.0f * s), 1e-8f);
                const float rt  = __builtin_amdgcn_rcpf(tt);
                const float s00 = (m00 + s) * rt;
                const float s01 = m01 * rt;
                const float s11 = (m11 + s) * rt;
                const float dS  = fmaxf(__builtin_fmaf(-s01, s01, s00 * s11), 1e-8f);
                const float rdS = __builtin_amdgcn_rcpf(dS);
                Ci00[ii][jj] = s11 * rdS;
                Ci01[ii][jj] = -s01 * rdS;
                Ci11[ii][jj] = s00 * rdS;
                Cm01[ii][jj] = m01;
                Cqd[ii][jj]  = -INV_SQRT_2PI * s01 * s01 * s01 * rdS;
                Cqj[ii][jj]  =  INV_SQRT_2PI * s00 * s00 * s11 * rdS;
                Cqi[ii][jj]  =  INV_SQRT_2PI * s00 * s11 * s11 * rdS;
                Cc2[ii][jj]  = 2.0f * INV_SQRT_2PI * INV_SQRT_2PI * s01 * s01;
            }
        }
    }

    float acc[2][2] = {{0.0f, 0.0f}, {0.0f, 0.0f}};

    auto elem = [&](int ii, int jj, float mi, float mjv, float Ei, float Ej) {
        float u1 = __builtin_fmaf(Ci01[ii][jj], mjv, Ci00[ii][jj] * mi);
        float u2 = __builtin_fmaf(Ci11[ii][jj], mjv, Ci01[ii][jj] * mi);
        float e1 = __builtin_amdgcn_exp2f(u1 * u1 * EXP2C);
        float e2 = __builtin_amdgcn_exp2f(u2 * u2 * EXP2C);
        float d1 = __builtin_fmaf(PHI_P, fabsf(u1), 1.0f);
        float d2 = __builtin_fmaf(PHI_P, fabsf(u2), 1.0f);
        float rp = __builtin_amdgcn_rcpf(d1 * d2);   // one rcp for both Phi's
        float t1 = d2 * rp;
        float t2 = d1 * rp;
        float hp1 = __builtin_fmaf(__builtin_fmaf(PHI_C3, t1, PHI_C2), t1, PHI_C1) * t1 * e1;
        float hp2 = __builtin_fmaf(__builtin_fmaf(PHI_C3, t2, PHI_C2), t2, PHI_C1) * t2 * e2;
        float Phi1 = 0.5f + __builtin_copysignf(0.5f - hp1, u1);
        float Phi2 = 0.5f + __builtin_copysignf(0.5f - hp2, u2);
        float a  = __builtin_fmaf(mi, mjv, Cm01[ii][jj]);
        float bb = __builtin_fmaf(Cqd[ii][jj], mi, Cqj[ii][jj] * mjv);
        float cc = __builtin_fmaf(Cqi[ii][jj], mi, Cqd[ii][jj] * mjv);
        float ta = __builtin_fmaf(a,  Phi1, bb * e1);
        float tb = __builtin_fmaf(cc, Phi1, Cc2[ii][jj] * e1);
        float& A = acc[ii][jj];
        A = __builtin_fmaf(Phi2, ta, A);
        A = __builtin_fmaf(e2,   tb, A);
        A = __builtin_fmaf(-Ei,  Ej, A);
    };

#pragma unroll
    for (int q = 0; q < 3; ++q) {
        const int co = c0 + q * 4;
        float4 mi4[2], Ei4[2], mj4[2], Ej4[2];
#pragma unroll
        for (int r = 0; r < 2; ++r) {
            mi4[r] = *(const float4*)(smi + (ia + r) * RSTR + co);
            Ei4[r] = *(const float4*)(sEi + (ia + r) * RSTR + co);
            mj4[r] = *(const float4*)(smj + (jb + r) * RSTR + co);
            Ej4[r] = *(const float4*)(sEj + (jb + r) * RSTR + co);
        }
#pragma unroll
        for (int ii = 0; ii < 2; ++ii) {
#pragma unroll
            for (int jj = 0; jj < 2; ++jj) {
                elem(ii, jj, mi4[ii].x, mj4[jj].x, Ei4[ii].x, Ej4[jj].x);
                elem(ii, jj, mi4[ii].y, mj4[jj].y, Ei4[ii].y, Ej4[jj].y);
                elem(ii, jj, mi4[ii].z, mj4[jj].z, Ei4[ii].z, Ej4[jj].z);
                elem(ii, jj, mi4[ii].w, mj4[jj].w, Ei4[ii].w, Ej4[jj].w);
            }
        }
    }

#pragma unroll
    for (int ii = 0; ii < 2; ++ii)
#pragma unroll
        for (int jj = 0; jj < 2; ++jj)
            red[ch * 256 + (ia + ii) * 16 + (jb + jj)] = acc[ii][jj];
    __syncthreads();

    if (tid < 256) {
        float sum = 0.0f;
#pragma unroll
        for (int k = 0; k < 8; ++k) sum += red[k * 256 + tid];
        const int i = ti * TT + (tid >> 4);
        const int j = tj * TT + (tid & 15);
        if (i < j) {
            float v = sum * (1.0f / 96.0f);
            out[COV_OFF + ((size_t)(b * NN + i)) * NN + j] = v;
            out[COV_OFF + ((size_t)(b * NN + j)) * NN + i] = v;
        }
    }
}

extern "C" void kernel_launch(void* const* d_in, const int* in_sizes, int n_in,
                              void* d_out, int out_size, void* d_ws, size_t ws_size,
                              hipStream_t stream) {
    const float* xin    = (const float*)d_in[0];
    const float* meanin = (const float*)d_in[1];
    const float* kin    = (const float*)d_in[2];
    float* out = (float*)d_out;

    relu_cov_fused<<<BSZ * NTILES, 512, 0, stream>>>(xin, meanin, kin, out);
}

// Round 11
// 75.205 us; speedup vs baseline: 1.0474x; 1.0226x over previous
//
#include <hip/hip_runtime.h>
#include <math.h>

#define BSZ 4
#define NN  256
#define CC  96
#define TT  16                 // tile side
#define NTILES 136             // 16*17/2 triangular tiles per batch
#define RSTR 100               // LDS row stride (floats): 16B-aligned, 2-way banks free
#define ARR  (TT * RSTR)       // 1600 floats per array

#define XIN_OFF  0
#define EH_OFF   2048          // BSZ*NN*2
#define COV_OFF  100352        // 2048 + BSZ*NN*CC

#define INV_SQRT_2PI 0.3989422804014327f
#define EXP2C       -0.7213475204444817f   // -0.5*log2(e)
// Row/Eh phases: Abramowitz-Stegun 7.1.25 (3-term), Phi abs err ~1.3e-5.
#define PHI_P   0.33267253f
#define PHI_C1  0.1740121f
#define PHI_C2 -0.0479399f
#define PHI_C3  0.3739278f
// Pair phase: clamped odd cubic-in-s fit of (Phi(u)-0.5)/u, s=u^2, fitted at
// Chebyshev nodes of [0,9] via Newton interpolation (verified vs normal
// table: |Phi err| <= ~4e-3 incl. the clamped tail). No rcp, no exp coupling.
#define PA0  0.39712f
#define PA1 -0.060411f
#define PA2  0.0061591f
#define PA3 -0.00025640f

__device__ __forceinline__ float phi_from_exp_s(float u, float e) {
    float t  = __builtin_amdgcn_rcpf(__builtin_fmaf(PHI_P, fabsf(u), 1.0f));
    float hp = __builtin_fmaf(__builtin_fmaf(PHI_C3, t, PHI_C2), t, PHI_C1) * t * e;
    return 0.5f + __builtin_copysignf(0.5f - hp, u);
}

// polynomial Phi, no transcendentals: 6 full-rate ops
__device__ __forceinline__ float phi_poly(float u) {
    float uc = fminf(fmaxf(u, -3.0f), 3.0f);     // v_med3_f32
    float s  = uc * uc;
    float P  = __builtin_fmaf(__builtin_fmaf(__builtin_fmaf(
                   PA3, s, PA2), s, PA1), s, PA0);
    return __builtin_fmaf(uc, P, 0.5f);
}

__device__ __forceinline__ int tri_offset(int k) {   // tiles before row k
    return k * TT - (k * (k - 1)) / 2;
}
__device__ __forceinline__ void tri_decode(int t, int& ti, int& tj) {
    float disc = 1089.0f - 8.0f * (float)t;          // (2T+1)^2 - 8t, T=16
    ti = (int)((33.0f - __builtin_amdgcn_sqrtf(disc)) * 0.5f);
    while (tri_offset(ti + 1) <= t) ++ti;            // float-precision fixup
    while (tri_offset(ti) > t) --ti;
    tj = ti + (t - tri_offset(ti));
}

// Single fused kernel. Pair phase: 2x2 pair sub-tile per thread
// (64 pair-threads x 8 c-chunks of 12), poly-Phi, 8-chunk LDS reduction.
__global__ __launch_bounds__(512) void relu_cov_fused(
    const float* __restrict__ xin, const float* __restrict__ meanin,
    const float* __restrict__ kin, float* __restrict__ out)
{
    const int blk = blockIdx.x;     // b*NTILES + t
    const int b   = blk / NTILES;
    const int t   = blk - b * NTILES;
    const int tid = threadIdx.x;

    int ti, tj;
    tri_decode(t, ti, tj);
    const bool diag = (ti == tj);

    __shared__ __align__(16) float lds[4 * ARR];   // [smi | sEi | smj | sEj]
    __shared__ float red[8 * 256];                 // [chunk][pair]
    __shared__ float srowS[32], srowR[32], srowV[32];
    float* const smi = lds;
    float* const sEi = lds + ARR;
    float* const smj = lds + 2 * ARR;
    float* const sEj = lds + 3 * ARR;

    // --- Phase 1: row consts + stage meanin ---
    if (tid < 32) {
        int row = (tid < 16) ? (ti * TT + tid) : (tj * TT + (tid - 16));
        float kd  = kin[((size_t)(b * NN + row)) * NN + row] + 1e-6f;
        float var = fmaxf(kd, 1e-8f);
        float st  = __builtin_amdgcn_sqrtf(var);
        srowV[tid] = var;
        srowS[tid] = st;
        srowR[tid] = __builtin_amdgcn_rcpf(st);
    }
#pragma unroll
    for (int it = 0; it < 2; ++it) {
        int k = tid + it * 512;         // 2 arrays x 16 rows x 24 float4 = 768
        if (k < 768) {
            int arr = k / 384;          // 0 = i-rows, 1 = j-rows
            int rem = k - arr * 384;
            int r   = rem / 24;
            int q   = rem - r * 24;
            int row = ((arr == 0) ? ti : tj) * TT + r;
            float4 v = *((const float4*)(meanin + ((size_t)(b * NN + row)) * CC) + q);
            *(float4*)(lds + arr * 2 * ARR + r * RSTR + q * 4) = v;
        }
    }
    __syncthreads();

    // --- Phase 2: Eh for 32 rows (accurate A&S path; feeds Eh output) ---
#pragma unroll
    for (int it = 0; it < 6; ++it) {
        int k   = tid + it * 512;
        int arr = k / 1536;
        int rem = k - arr * 1536;
        int r   = rem / 96;
        int c   = rem - r * 96;
        float m  = lds[arr * 2 * ARR + r * RSTR + c];
        float st = srowS[arr * 16 + r];
        float rs = srowR[arr * 16 + r];
        float z  = m * rs;
        float e  = __builtin_amdgcn_exp2f(z * z * EXP2C);
        float Ph = phi_from_exp_s(z, e);
        float Eh = __builtin_fmaf(m, Ph, st * (INV_SQRT_2PI * e));
        lds[(arr * 2 + 1) * ARR + r * RSTR + c] = Eh;
    }
    __syncthreads();

    // --- Phase 2b: diagonal-tile global outputs ---
    if (diag) {
#pragma unroll
        for (int it = 0; it < 3; ++it) {         // Eh output: 16 x 96
            int k = tid + it * 512;
            int r = k / 96, c = k - r * 96;
            out[EH_OFF + ((size_t)(b * NN + ti * TT + r)) * CC + c] = sEi[r * RSTR + c];
        }
        if (tid < 32) {                          // xin copy: 16 rows x 2
            int r = tid >> 1, d = tid & 1;
            size_t o = ((size_t)(b * NN + ti * TT + r)) * 2 + d;
            out[XIN_OFF + o] = xin[o];
        }
        {                                        // dvals: tid = r*32 + s, 3 c each
            int r = tid >> 5, s = tid & 31;
            float st = srowS[r], var = srowV[r], rs = srowR[r];
            float dsum = 0.0f;
#pragma unroll
            for (int dc = 0; dc < 3; ++dc) {
                int c = s * 3 + dc;
                float m  = smi[r * RSTR + c];
                float Eh = sEi[r * RSTR + c];
                float z  = m * rs;
                float e  = __builtin_amdgcn_exp2f(z * z * EXP2C);
                float Ph = phi_from_exp_s(z, e);
                float ph = INV_SQRT_2PI * e;
                float dt = __builtin_fmaf(__builtin_fmaf(m, m, var), Ph,
                           __builtin_fmaf(m * st, ph, -Eh * Eh));
                dsum += dt;
            }
            dsum += __shfl_down(dsum, 16, 32);
            dsum += __shfl_down(dsum,  8, 32);
            dsum += __shfl_down(dsum,  4, 32);
            dsum += __shfl_down(dsum,  2, 32);
            dsum += __shfl_down(dsum,  1, 32);
            if (s == 0) {
                float dval = fmaxf(dsum * (1.0f / 96.0f), 1e-6f);
                int row = ti * TT + r;
                out[COV_OFF + ((size_t)(b * NN + row)) * NN + row] = dval + 1e-6f;
            }
        }
    }

    // --- Phase 3: pair loop, 2x2 pairs per thread, poly-Phi (2 trans/elem) ---
    const int pt = tid & 63;        // pair-thread
    const int ch = tid >> 6;        // c-chunk 0..7 (12 c each)
    const int ia = (pt >> 3) * 2;   // i_loc base (0,2,..,14)
    const int jb = (pt & 7) * 2;    // j_loc base
    const int c0 = ch * 12;

    // per-pair constants [ii][jj]
    float Ci00[2][2], Ci01[2][2], Ci11[2][2], Cm01[2][2];
    float Cqd[2][2], Cqj[2][2], Cqi[2][2], Cc2[2][2];
    {
        const float* kb = kin + (size_t)b * NN * NN;
#pragma unroll
        for (int ii = 0; ii < 2; ++ii) {
            const int gi = ti * TT + ia + ii;
            const float m00 = srowV[ia + ii];
            float2 k2 = *(const float2*)(kb + (size_t)gi * NN + tj * TT + jb);
#pragma unroll
            for (int jj = 0; jj < 2; ++jj) {
                const float m11 = srowV[16 + jb + jj];
                const float m01 = (jj == 0) ? k2.x : k2.y;
                const float det = __builtin_fmaf(-m01, m01, m00 * m11);
                const float s   = __builtin_amdgcn_sqrtf(fmaxf(det, 1e-8f));
                const float tt  = fmaxf(__builtin_amdgcn_sqrtf(m00 + m11 + 2.0f * s), 1e-8f);
                const float rt  = __builtin_amdgcn_rcpf(tt);
                const float s00 = (m00 + s) * rt;
                const float s01 = m01 * rt;
                const float s11 = (m11 + s) * rt;
                const float dS  = fmaxf(__builtin_fmaf(-s01, s01, s00 * s11), 1e-8f);
                const float rdS = __builtin_amdgcn_rcpf(dS);
                Ci00[ii][jj] = s11 * rdS;
                Ci01[ii][jj] = -s01 * rdS;
                Ci11[ii][jj] = s00 * rdS;
                Cm01[ii][jj] = m01;
                Cqd[ii][jj]  = -INV_SQRT_2PI * s01 * s01 * s01 * rdS;
                Cqj[ii][jj]  =  INV_SQRT_2PI * s00 * s00 * s11 * rdS;
                Cqi[ii][jj]  =  INV_SQRT_2PI * s00 * s11 * s11 * rdS;
                Cc2[ii][jj]  = 2.0f * INV_SQRT_2PI * INV_SQRT_2PI * s01 * s01;
            }
        }
    }

    float acc[2][2] = {{0.0f, 0.0f}, {0.0f, 0.0f}};

    auto elem = [&](int ii, int jj, float mi, float mjv, float Ei, float Ej) {
        float u1 = __builtin_fmaf(Ci01[ii][jj], mjv, Ci00[ii][jj] * mi);
        float u2 = __builtin_fmaf(Ci11[ii][jj], mjv, Ci01[ii][jj] * mi);
        float e1 = __builtin_amdgcn_exp2f(u1 * u1 * EXP2C);
        float e2 = __builtin_amdgcn_exp2f(u2 * u2 * EXP2C);
        float Phi1 = phi_poly(u1);
        float Phi2 = phi_poly(u2);
        float a  = __builtin_fmaf(mi, mjv, Cm01[ii][jj]);
        float bb = __builtin_fmaf(Cqd[ii][jj], mi, Cqj[ii][jj] * mjv);
        float cc = __builtin_fmaf(Cqi[ii][jj], mi, Cqd[ii][jj] * mjv);
        float ta = __builtin_fmaf(a,  Phi1, bb * e1);
        float tb = __builtin_fmaf(cc, Phi1, Cc2[ii][jj] * e1);
        float& A = acc[ii][jj];
        A = __builtin_fmaf(Phi2, ta, A);
        A = __builtin_fmaf(e2,   tb, A);
        A = __builtin_fmaf(-Ei,  Ej, A);
    };

#pragma unroll
    for (int q = 0; q < 3; ++q) {
        const int co = c0 + q * 4;
        float4 mi4[2], Ei4[2], mj4[2], Ej4[2];
#pragma unroll
        for (int r = 0; r < 2; ++r) {
            mi4[r] = *(const float4*)(smi + (ia + r) * RSTR + co);
            Ei4[r] = *(const float4*)(sEi + (ia + r) * RSTR + co);
            mj4[r] = *(const float4*)(smj + (jb + r) * RSTR + co);
            Ej4[r] = *(const float4*)(sEj + (jb + r) * RSTR + co);
        }
#pragma unroll
        for (int ii = 0; ii < 2; ++ii) {
#pragma unroll
            for (int jj = 0; jj < 2; ++jj) {
                elem(ii, jj, mi4[ii].x, mj4[jj].x, Ei4[ii].x, Ej4[jj].x);
                elem(ii, jj, mi4[ii].y, mj4[jj].y, Ei4[ii].y, Ej4[jj].y);
                elem(ii, jj, mi4[ii].z, mj4[jj].z, Ei4[ii].z, Ej4[jj].z);
                elem(ii, jj, mi4[ii].w, mj4[jj].w, Ei4[ii].w, Ej4[jj].w);
            }
        }
    }

#pragma unroll
    for (int ii = 0; ii < 2; ++ii)
#pragma unroll
        for (int jj = 0; jj < 2; ++jj)
            red[ch * 256 + (ia + ii) * 16 + (jb + jj)] = acc[ii][jj];
    __syncthreads();

    if (tid < 256) {
        float sum = 0.0f;
#pragma unroll
        for (int k = 0; k < 8; ++k) sum += red[k * 256 + tid];
        const int i = ti * TT + (tid >> 4);
        const int j = tj * TT + (tid & 15);
        if (i < j) {
            float v = sum * (1.0f / 96.0f);
            out[COV_OFF + ((size_t)(b * NN + i)) * NN + j] = v;
            out[COV_OFF + ((size_t)(b * NN + j)) * NN + i] = v;
        }
    }
}

extern "C" void kernel_launch(void* const* d_in, const int* in_sizes, int n_in,
                              void* d_out, int out_size, void* d_ws, size_t ws_size,
                              hipStream_t stream) {
    const float* xin    = (const float*)d_in[0];
    const float* meanin = (const float*)d_in[1];
    const float* kin    = (const float*)d_in[2];
    float* out = (float*)d_out;

    relu_cov_fused<<<BSZ * NTILES, 512, 0, stream>>>(xin, meanin, kin, out);
}

// Round 12
// 74.166 us; speedup vs baseline: 1.0620x; 1.0140x over previous
//
#include <hip/hip_runtime.h>
#include <math.h>

#define BSZ 4
#define NN  256
#define CC  96
#define TT  16                 // tile side
#define NTILES 136             // 16*17/2 triangular tiles per batch
#define RSTR 100               // LDS row stride (floats): 16B-aligned, 2-way banks free
#define ARR  (TT * RSTR)       // 1600 floats per array

#define XIN_OFF  0
#define EH_OFF   2048          // BSZ*NN*2
#define COV_OFF  100352        // 2048 + BSZ*NN*CC

#define INV_SQRT_2PI 0.3989422804014327f
#define EXP2C       -0.7213475204444817f   // -0.5*log2(e)
// Row/Eh phases: Abramowitz-Stegun 7.1.25 (3-term), Phi abs err ~1.3e-5.
#define PHI_P   0.33267253f
#define PHI_C1  0.1740121f
#define PHI_C2 -0.0479399f
#define PHI_C3  0.3739278f
// Pair phase: clamped odd cubic-in-s fit of (Phi(u)-0.5)/u, s=u^2 (R11).
#define PA0  0.39712f
#define PA1 -0.060411f
#define PA2  0.0061591f
#define PA3 -0.00025640f

typedef float v2f __attribute__((ext_vector_type(2)));

__device__ __forceinline__ v2f v2s(float s) { v2f r; r.x = s; r.y = s; return r; }

#if __has_builtin(__builtin_elementwise_fma)
#define V2FMA(a, b, c) __builtin_elementwise_fma((v2f)(a), (v2f)(b), (v2f)(c))
#else
#define V2FMA(a, b, c) ((a) * (b) + (c))
#endif

__device__ __forceinline__ float phi_from_exp_s(float u, float e) {
    float t  = __builtin_amdgcn_rcpf(__builtin_fmaf(PHI_P, fabsf(u), 1.0f));
    float hp = __builtin_fmaf(__builtin_fmaf(PHI_C3, t, PHI_C2), t, PHI_C1) * t * e;
    return 0.5f + __builtin_copysignf(0.5f - hp, u);
}

__device__ __forceinline__ int tri_offset(int k) {   // tiles before row k
    return k * TT - (k * (k - 1)) / 2;
}
__device__ __forceinline__ void tri_decode(int t, int& ti, int& tj) {
    float disc = 1089.0f - 8.0f * (float)t;          // (2T+1)^2 - 8t, T=16
    ti = (int)((33.0f - __builtin_amdgcn_sqrtf(disc)) * 0.5f);
    while (tri_offset(ti + 1) <= t) ++ti;            // float-precision fixup
    while (tri_offset(ti) > t) --ti;
    tj = ti + (t - tri_offset(ti));
}

// Single fused kernel. Pair phase: 2x2 pair sub-tile per thread, c packed in
// pairs (v2f -> VOP3P v_pk_*_f32); exp2 and med3-clamp remain scalar.
__global__ __launch_bounds__(512) void relu_cov_fused(
    const float* __restrict__ xin, const float* __restrict__ meanin,
    const float* __restrict__ kin, float* __restrict__ out)
{
    const int blk = blockIdx.x;     // b*NTILES + t
    const int b   = blk / NTILES;
    const int t   = blk - b * NTILES;
    const int tid = threadIdx.x;

    int ti, tj;
    tri_decode(t, ti, tj);
    const bool diag = (ti == tj);

    __shared__ __align__(16) float lds[4 * ARR];   // [smi | sEi | smj | sEj]
    __shared__ float red[8 * 256];                 // [chunk][pair]
    __shared__ float srowS[32], srowR[32], srowV[32];
    float* const smi = lds;
    float* const sEi = lds + ARR;
    float* const smj = lds + 2 * ARR;
    float* const sEj = lds + 3 * ARR;

    // --- Phase 1: row consts + stage meanin ---
    if (tid < 32) {
        int row = (tid < 16) ? (ti * TT + tid) : (tj * TT + (tid - 16));
        float kd  = kin[((size_t)(b * NN + row)) * NN + row] + 1e-6f;
        float var = fmaxf(kd, 1e-8f);
        float st  = __builtin_amdgcn_sqrtf(var);
        srowV[tid] = var;
        srowS[tid] = st;
        srowR[tid] = __builtin_amdgcn_rcpf(st);
    }
#pragma unroll
    for (int it = 0; it < 2; ++it) {
        int k = tid + it * 512;         // 2 arrays x 16 rows x 24 float4 = 768
        if (k < 768) {
            int arr = k / 384;          // 0 = i-rows, 1 = j-rows
            int rem = k - arr * 384;
            int r   = rem / 24;
            int q   = rem - r * 24;
            int row = ((arr == 0) ? ti : tj) * TT + r;
            float4 v = *((const float4*)(meanin + ((size_t)(b * NN + row)) * CC) + q);
            *(float4*)(lds + arr * 2 * ARR + r * RSTR + q * 4) = v;
        }
    }
    __syncthreads();

    // --- Phase 2: Eh for 32 rows (accurate A&S path; feeds Eh output) ---
#pragma unroll
    for (int it = 0; it < 6; ++it) {
        int k   = tid + it * 512;
        int arr = k / 1536;
        int rem = k - arr * 1536;
        int r   = rem / 96;
        int c   = rem - r * 96;
        float m  = lds[arr * 2 * ARR + r * RSTR + c];
        float st = srowS[arr * 16 + r];
        float rs = srowR[arr * 16 + r];
        float z  = m * rs;
        float e  = __builtin_amdgcn_exp2f(z * z * EXP2C);
        float Ph = phi_from_exp_s(z, e);
        float Eh = __builtin_fmaf(m, Ph, st * (INV_SQRT_2PI * e));
        lds[(arr * 2 + 1) * ARR + r * RSTR + c] = Eh;
    }
    __syncthreads();

    // --- Phase 2b: diagonal-tile global outputs ---
    if (diag) {
#pragma unroll
        for (int it = 0; it < 3; ++it) {         // Eh output: 16 x 96
            int k = tid + it * 512;
            int r = k / 96, c = k - r * 96;
            out[EH_OFF + ((size_t)(b * NN + ti * TT + r)) * CC + c] = sEi[r * RSTR + c];
        }
        if (tid < 32) {                          // xin copy: 16 rows x 2
            int r = tid >> 1, d = tid & 1;
            size_t o = ((size_t)(b * NN + ti * TT + r)) * 2 + d;
            out[XIN_OFF + o] = xin[o];
        }
        {                                        // dvals: tid = r*32 + s, 3 c each
            int r = tid >> 5, s = tid & 31;
            float st = srowS[r], var = srowV[r], rs = srowR[r];
            float dsum = 0.0f;
#pragma unroll
            for (int dc = 0; dc < 3; ++dc) {
                int c = s * 3 + dc;
                float m  = smi[r * RSTR + c];
                float Eh = sEi[r * RSTR + c];
                float z  = m * rs;
                float e  = __builtin_amdgcn_exp2f(z * z * EXP2C);
                float Ph = phi_from_exp_s(z, e);
                float ph = INV_SQRT_2PI * e;
                float dt = __builtin_fmaf(__builtin_fmaf(m, m, var), Ph,
                           __builtin_fmaf(m * st, ph, -Eh * Eh));
                dsum += dt;
            }
            dsum += __shfl_down(dsum, 16, 32);
            dsum += __shfl_down(dsum,  8, 32);
            dsum += __shfl_down(dsum,  4, 32);
            dsum += __shfl_down(dsum,  2, 32);
            dsum += __shfl_down(dsum,  1, 32);
            if (s == 0) {
                float dval = fmaxf(dsum * (1.0f / 96.0f), 1e-6f);
                int row = ti * TT + r;
                out[COV_OFF + ((size_t)(b * NN + row)) * NN + row] = dval + 1e-6f;
            }
        }
    }

    // --- Phase 3: pair loop, 2x2 pairs per thread, packed c-pairs ---
    const int pt = tid & 63;        // pair-thread
    const int ch = tid >> 6;        // c-chunk 0..7 (12 c each)
    const int ia = (pt >> 3) * 2;   // i_loc base (0,2,..,14)
    const int jb = (pt & 7) * 2;    // j_loc base
    const int c0 = ch * 12;

    // per-pair constants [ii][jj]
    float Ci00[2][2], Ci01[2][2], Ci11[2][2], Cm01[2][2];
    float Cqd[2][2], Cqj[2][2], Cqi[2][2], Cc2[2][2];
    {
        const float* kb = kin + (size_t)b * NN * NN;
#pragma unroll
        for (int ii = 0; ii < 2; ++ii) {
            const int gi = ti * TT + ia + ii;
            const float m00 = srowV[ia + ii];
            float2 k2 = *(const float2*)(kb + (size_t)gi * NN + tj * TT + jb);
#pragma unroll
            for (int jj = 0; jj < 2; ++jj) {
                const float m11 = srowV[16 + jb + jj];
                const float m01 = (jj == 0) ? k2.x : k2.y;
                const float det = __builtin_fmaf(-m01, m01, m00 * m11);
                const float s   = __builtin_amdgcn_sqrtf(fmaxf(det, 1e-8f));
                const float tt  = fmaxf(__builtin_amdgcn_sqrtf(m00 + m11 + 2.0f * s), 1e-8f);
                const float rt  = __builtin_amdgcn_rcpf(tt);
                const float s00 = (m00 + s) * rt;
                const float s01 = m01 * rt;
                const float s11 = (m11 + s) * rt;
                const float dS  = fmaxf(__builtin_fmaf(-s01, s01, s00 * s11), 1e-8f);
                const float rdS = __builtin_amdgcn_rcpf(dS);
                Ci00[ii][jj] = s11 * rdS;
                Ci01[ii][jj] = -s01 * rdS;
                Ci11[ii][jj] = s00 * rdS;
                Cm01[ii][jj] = m01;
                Cqd[ii][jj]  = -INV_SQRT_2PI * s01 * s01 * s01 * rdS;
                Cqj[ii][jj]  =  INV_SQRT_2PI * s00 * s00 * s11 * rdS;
                Cqi[ii][jj]  =  INV_SQRT_2PI * s00 * s11 * s11 * rdS;
                Cc2[ii][jj]  = 2.0f * INV_SQRT_2PI * INV_SQRT_2PI * s01 * s01;
            }
        }
    }

    v2f acc[2][2] = {{v2s(0.0f), v2s(0.0f)}, {v2s(0.0f), v2s(0.0f)}};

    // packed elem: 2 c's per call, all heavy math on v2f (VOP3P);
    // exp2 and the med3 clamp are scalar per component.
    auto elem2 = [&](int ii, int jj, v2f mi, v2f mj, v2f Ei, v2f Ej) {
        v2f u1 = V2FMA(v2s(Ci01[ii][jj]), mj, v2s(Ci00[ii][jj]) * mi);
        v2f u2 = V2FMA(v2s(Ci11[ii][jj]), mj, v2s(Ci01[ii][jj]) * mi);
        v2f g1 = u1 * u1 * v2s(EXP2C);
        v2f g2 = u2 * u2 * v2s(EXP2C);
        v2f e1, e2;
        e1.x = __builtin_amdgcn_exp2f(g1.x);  e1.y = __builtin_amdgcn_exp2f(g1.y);
        e2.x = __builtin_amdgcn_exp2f(g2.x);  e2.y = __builtin_amdgcn_exp2f(g2.y);
        v2f uc1, uc2;                         // scalar med3 clamps
        uc1.x = fminf(fmaxf(u1.x, -3.0f), 3.0f);
        uc1.y = fminf(fmaxf(u1.y, -3.0f), 3.0f);
        uc2.x = fminf(fmaxf(u2.x, -3.0f), 3.0f);
        uc2.y = fminf(fmaxf(u2.y, -3.0f), 3.0f);
        v2f s1 = uc1 * uc1;
        v2f s2 = uc2 * uc2;
        v2f P1 = V2FMA(V2FMA(V2FMA(v2s(PA3), s1, v2s(PA2)), s1, v2s(PA1)), s1, v2s(PA0));
        v2f P2 = V2FMA(V2FMA(V2FMA(v2s(PA3), s2, v2s(PA2)), s2, v2s(PA1)), s2, v2s(PA0));
        v2f Phi1 = V2FMA(uc1, P1, v2s(0.5f));
        v2f Phi2 = V2FMA(uc2, P2, v2s(0.5f));
        v2f a  = V2FMA(mi, mj, v2s(Cm01[ii][jj]));
        v2f bb = V2FMA(v2s(Cqd[ii][jj]), mi, v2s(Cqj[ii][jj]) * mj);
        v2f cc = V2FMA(v2s(Cqi[ii][jj]), mi, v2s(Cqd[ii][jj]) * mj);
        v2f ta = V2FMA(a,  Phi1, bb * e1);
        v2f tb = V2FMA(cc, Phi1, v2s(Cc2[ii][jj]) * e1);
        v2f A  = acc[ii][jj];
        A = V2FMA(Phi2, ta, A);
        A = V2FMA(e2,   tb, A);
        A = V2FMA(-Ei,  Ej, A);
        acc[ii][jj] = A;
    };

#pragma unroll
    for (int q = 0; q < 3; ++q) {
        const int co = c0 + q * 4;
        float4 mi4[2], Ei4[2], mj4[2], Ej4[2];
#pragma unroll
        for (int r = 0; r < 2; ++r) {
            mi4[r] = *(const float4*)(smi + (ia + r) * RSTR + co);
            Ei4[r] = *(const float4*)(sEi + (ia + r) * RSTR + co);
            mj4[r] = *(const float4*)(smj + (jb + r) * RSTR + co);
            Ej4[r] = *(const float4*)(sEj + (jb + r) * RSTR + co);
        }
#pragma unroll
        for (int ii = 0; ii < 2; ++ii) {
#pragma unroll
            for (int jj = 0; jj < 2; ++jj) {
                v2f miL = {mi4[ii].x, mi4[ii].y}, miH = {mi4[ii].z, mi4[ii].w};
                v2f mjL = {mj4[jj].x, mj4[jj].y}, mjH = {mj4[jj].z, mj4[jj].w};
                v2f EiL = {Ei4[ii].x, Ei4[ii].y}, EiH = {Ei4[ii].z, Ei4[ii].w};
                v2f EjL = {Ej4[jj].x, Ej4[jj].y}, EjH = {Ej4[jj].z, Ej4[jj].w};
                elem2(ii, jj, miL, mjL, EiL, EjL);
                elem2(ii, jj, miH, mjH, EiH, EjH);
            }
        }
    }

#pragma unroll
    for (int ii = 0; ii < 2; ++ii)
#pragma unroll
        for (int jj = 0; jj < 2; ++jj)
            red[ch * 256 + (ia + ii) * 16 + (jb + jj)] =
                acc[ii][jj].x + acc[ii][jj].y;
    __syncthreads();

    if (tid < 256) {
        float sum = 0.0f;
#pragma unroll
        for (int k = 0; k < 8; ++k) sum += red[k * 256 + tid];
        const int i = ti * TT + (tid >> 4);
        const int j = tj * TT + (tid & 15);
        if (i < j) {
            float v = sum * (1.0f / 96.0f);
            out[COV_OFF + ((size_t)(b * NN + i)) * NN + j] = v;
            out[COV_OFF + ((size_t)(b * NN + j)) * NN + i] = v;
        }
    }
}

extern "C" void kernel_launch(void* const* d_in, const int* in_sizes, int n_in,
                              void* d_out, int out_size, void* d_ws, size_t ws_size,
                              hipStream_t stream) {
    const float* xin    = (const float*)d_in[0];
    const float* meanin = (const float*)d_in[1];
    const float* kin    = (const float*)d_in[2];
    float* out = (float*)d_out;

    relu_cov_fused<<<BSZ * NTILES, 512, 0, stream>>>(xin, meanin, kin, out);
}

// Round 13
// 73.107 us; speedup vs baseline: 1.0774x; 1.0145x over previous
//
#include <hip/hip_runtime.h>
#include <math.h>

#define BSZ 4
#define NN  256
#define CC  96
#define TT  16                 // tile side
#define NTILES 136             // 16*17/2 triangular tiles per batch
#define RSTR 100               // LDS row stride (floats): 16B-aligned, 2-way banks free
#define ARR  (TT * RSTR)       // 1600 floats per array

#define XIN_OFF  0
#define EH_OFF   2048          // BSZ*NN*2
#define COV_OFF  100352        // 2048 + BSZ*NN*CC

#define INV_SQRT_2PI 0.3989422804014327f
#define EXP2C       -0.7213475204444817f   // -0.5*log2(e)
// Row/Eh phases: Abramowitz-Stegun 7.1.25 (3-term), Phi abs err ~1.3e-5.
#define PHI_P   0.33267253f
#define PHI_C1  0.1740121f
#define PHI_C2 -0.0479399f
#define PHI_C3  0.3739278f
// Pair phase Phi: clamped odd cubic-in-s fit of (Phi(u)-0.5)/u, s=u^2 (R11).
#define PA0  0.39712f
#define PA1 -0.060411f
#define PA2  0.0061591f
#define PA3 -0.00025640f
// Pair phase pdf: quartic Chebyshev fit of exp(-s/2), s=u^2 in [0,9]
// (clamped via uc). Derived from Bessel expansion of exp(2.25 z); verified
// at s={0,1,2.25,4,9}: err {-4.8e-3,+3.2e-3,-2.7e-3,-1.4e-3,+3.2e-3}.
#define PB0  0.99521f
#define PB1 -0.471073f
#define PB2  0.0955511f
#define PB3 -0.00930823f
#define PB4  0.000351287f

typedef float v2f __attribute__((ext_vector_type(2)));

__device__ __forceinline__ v2f v2s(float s) { v2f r; r.x = s; r.y = s; return r; }

#if __has_builtin(__builtin_elementwise_fma)
#define V2FMA(a, b, c) __builtin_elementwise_fma((v2f)(a), (v2f)(b), (v2f)(c))
#else
#define V2FMA(a, b, c) ((a) * (b) + (c))
#endif

__device__ __forceinline__ float phi_from_exp_s(float u, float e) {
    float t  = __builtin_amdgcn_rcpf(__builtin_fmaf(PHI_P, fabsf(u), 1.0f));
    float hp = __builtin_fmaf(__builtin_fmaf(PHI_C3, t, PHI_C2), t, PHI_C1) * t * e;
    return 0.5f + __builtin_copysignf(0.5f - hp, u);
}

__device__ __forceinline__ int tri_offset(int k) {   // tiles before row k
    return k * TT - (k * (k - 1)) / 2;
}
__device__ __forceinline__ void tri_decode(int t, int& ti, int& tj) {
    float disc = 1089.0f - 8.0f * (float)t;          // (2T+1)^2 - 8t, T=16
    ti = (int)((33.0f - __builtin_amdgcn_sqrtf(disc)) * 0.5f);
    while (tri_offset(ti + 1) <= t) ++ti;            // float-precision fixup
    while (tri_offset(ti) > t) --ti;
    tj = ti + (t - tri_offset(ti));
}

// Single fused kernel. Pair phase: 2x2 pair sub-tile per thread, c packed in
// pairs (VOP3P), Phi AND pdf both clamped polynomials — zero transcendentals
// in the inner loop; only the med3 clamps are scalar.
__global__ __launch_bounds__(512) void relu_cov_fused(
    const float* __restrict__ xin, const float* __restrict__ meanin,
    const float* __restrict__ kin, float* __restrict__ out)
{
    const int blk = blockIdx.x;     // b*NTILES + t
    const int b   = blk / NTILES;
    const int t   = blk - b * NTILES;
    const int tid = threadIdx.x;

    int ti, tj;
    tri_decode(t, ti, tj);
    const bool diag = (ti == tj);

    __shared__ __align__(16) float lds[4 * ARR];   // [smi | sEi | smj | sEj]
    __shared__ float red[8 * 256];                 // [chunk][pair]
    __shared__ float srowS[32], srowR[32], srowV[32];
    float* const smi = lds;
    float* const sEi = lds + ARR;
    float* const smj = lds + 2 * ARR;
    float* const sEj = lds + 3 * ARR;

    // --- Phase 1: row consts + stage meanin ---
    if (tid < 32) {
        int row = (tid < 16) ? (ti * TT + tid) : (tj * TT + (tid - 16));
        float kd  = kin[((size_t)(b * NN + row)) * NN + row] + 1e-6f;
        float var = fmaxf(kd, 1e-8f);
        float st  = __builtin_amdgcn_sqrtf(var);
        srowV[tid] = var;
        srowS[tid] = st;
        srowR[tid] = __builtin_amdgcn_rcpf(st);
    }
#pragma unroll
    for (int it = 0; it < 2; ++it) {
        int k = tid + it * 512;         // 2 arrays x 16 rows x 24 float4 = 768
        if (k < 768) {
            int arr = k / 384;          // 0 = i-rows, 1 = j-rows
            int rem = k - arr * 384;
            int r   = rem / 24;
            int q   = rem - r * 24;
            int row = ((arr == 0) ? ti : tj) * TT + r;
            float4 v = *((const float4*)(meanin + ((size_t)(b * NN + row)) * CC) + q);
            *(float4*)(lds + arr * 2 * ARR + r * RSTR + q * 4) = v;
        }
    }
    __syncthreads();

    // --- Phase 2: Eh for 32 rows (accurate A&S path; feeds Eh output) ---
#pragma unroll
    for (int it = 0; it < 6; ++it) {
        int k   = tid + it * 512;
        int arr = k / 1536;
        int rem = k - arr * 1536;
        int r   = rem / 96;
        int c   = rem - r * 96;
        float m  = lds[arr * 2 * ARR + r * RSTR + c];
        float st = srowS[arr * 16 + r];
        float rs = srowR[arr * 16 + r];
        float z  = m * rs;
        float e  = __builtin_amdgcn_exp2f(z * z * EXP2C);
        float Ph = phi_from_exp_s(z, e);
        float Eh = __builtin_fmaf(m, Ph, st * (INV_SQRT_2PI * e));
        lds[(arr * 2 + 1) * ARR + r * RSTR + c] = Eh;
    }
    __syncthreads();

    // --- Phase 2b: diagonal-tile global outputs ---
    if (diag) {
#pragma unroll
        for (int it = 0; it < 3; ++it) {         // Eh output: 16 x 96
            int k = tid + it * 512;
            int r = k / 96, c = k - r * 96;
            out[EH_OFF + ((size_t)(b * NN + ti * TT + r)) * CC + c] = sEi[r * RSTR + c];
        }
        if (tid < 32) {                          // xin copy: 16 rows x 2
            int r = tid >> 1, d = tid & 1;
            size_t o = ((size_t)(b * NN + ti * TT + r)) * 2 + d;
            out[XIN_OFF + o] = xin[o];
        }
        {                                        // dvals: tid = r*32 + s, 3 c each
            int r = tid >> 5, s = tid & 31;
            float st = srowS[r], var = srowV[r], rs = srowR[r];
            float dsum = 0.0f;
#pragma unroll
            for (int dc = 0; dc < 3; ++dc) {
                int c = s * 3 + dc;
                float m  = smi[r * RSTR + c];
                float Eh = sEi[r * RSTR + c];
                float z  = m * rs;
                float e  = __builtin_amdgcn_exp2f(z * z * EXP2C);
                float Ph = phi_from_exp_s(z, e);
                float ph = INV_SQRT_2PI * e;
                float dt = __builtin_fmaf(__builtin_fmaf(m, m, var), Ph,
                           __builtin_fmaf(m * st, ph, -Eh * Eh));
                dsum += dt;
            }
            dsum += __shfl_down(dsum, 16, 32);
            dsum += __shfl_down(dsum,  8, 32);
            dsum += __shfl_down(dsum,  4, 32);
            dsum += __shfl_down(dsum,  2, 32);
            dsum += __shfl_down(dsum,  1, 32);
            if (s == 0) {
                float dval = fmaxf(dsum * (1.0f / 96.0f), 1e-6f);
                int row = ti * TT + r;
                out[COV_OFF + ((size_t)(b * NN + row)) * NN + row] = dval + 1e-6f;
            }
        }
    }

    // --- Phase 3: pair loop, 2x2 pairs per thread, packed, trans-free ---
    const int pt = tid & 63;        // pair-thread
    const int ch = tid >> 6;        // c-chunk 0..7 (12 c each)
    const int ia = (pt >> 3) * 2;   // i_loc base (0,2,..,14)
    const int jb = (pt & 7) * 2;    // j_loc base
    const int c0 = ch * 12;

    // per-pair constants [ii][jj]
    float Ci00[2][2], Ci01[2][2], Ci11[2][2], Cm01[2][2];
    float Cqd[2][2], Cqj[2][2], Cqi[2][2], Cc2[2][2];
    {
        const float* kb = kin + (size_t)b * NN * NN;
#pragma unroll
        for (int ii = 0; ii < 2; ++ii) {
            const int gi = ti * TT + ia + ii;
            const float m00 = srowV[ia + ii];
            float2 k2 = *(const float2*)(kb + (size_t)gi * NN + tj * TT + jb);
#pragma unroll
            for (int jj = 0; jj < 2; ++jj) {
                const float m11 = srowV[16 + jb + jj];
                const float m01 = (jj == 0) ? k2.x : k2.y;
                const float det = __builtin_fmaf(-m01, m01, m00 * m11);
                const float s   = __builtin_amdgcn_sqrtf(fmaxf(det, 1e-8f));
                const float tt  = fmaxf(__builtin_amdgcn_sqrtf(m00 + m11 + 2.0f * s), 1e-8f);
                const float rt  = __builtin_amdgcn_rcpf(tt);
                const float s00 = (m00 + s) * rt;
                const float s01 = m01 * rt;
                const float s11 = (m11 + s) * rt;
                const float dS  = fmaxf(__builtin_fmaf(-s01, s01, s00 * s11), 1e-8f);
                const float rdS = __builtin_amdgcn_rcpf(dS);
                Ci00[ii][jj] = s11 * rdS;
                Ci01[ii][jj] = -s01 * rdS;
                Ci11[ii][jj] = s00 * rdS;
                Cm01[ii][jj] = m01;
                Cqd[ii][jj]  = -INV_SQRT_2PI * s01 * s01 * s01 * rdS;
                Cqj[ii][jj]  =  INV_SQRT_2PI * s00 * s00 * s11 * rdS;
                Cqi[ii][jj]  =  INV_SQRT_2PI * s00 * s11 * s11 * rdS;
                Cc2[ii][jj]  = 2.0f * INV_SQRT_2PI * INV_SQRT_2PI * s01 * s01;
            }
        }
    }

    v2f acc[2][2] = {{v2s(0.0f), v2s(0.0f)}, {v2s(0.0f), v2s(0.0f)}};

    // packed elem: 2 c's per call; only the med3 clamps are scalar.
    auto elem2 = [&](int ii, int jj, v2f mi, v2f mj, v2f Ei, v2f Ej) {
        v2f u1 = V2FMA(v2s(Ci01[ii][jj]), mj, v2s(Ci00[ii][jj]) * mi);
        v2f u2 = V2FMA(v2s(Ci11[ii][jj]), mj, v2s(Ci01[ii][jj]) * mi);
        v2f uc1, uc2;                         // scalar med3 clamps
        uc1.x = fminf(fmaxf(u1.x, -3.0f), 3.0f);
        uc1.y = fminf(fmaxf(u1.y, -3.0f), 3.0f);
        uc2.x = fminf(fmaxf(u2.x, -3.0f), 3.0f);
        uc2.y = fminf(fmaxf(u2.y, -3.0f), 3.0f);
        v2f s1 = uc1 * uc1;
        v2f s2 = uc2 * uc2;
        // Phi polys
        v2f P1 = V2FMA(V2FMA(V2FMA(v2s(PA3), s1, v2s(PA2)), s1, v2s(PA1)), s1, v2s(PA0));
        v2f P2 = V2FMA(V2FMA(V2FMA(v2s(PA3), s2, v2s(PA2)), s2, v2s(PA1)), s2, v2s(PA0));
        v2f Phi1 = V2FMA(uc1, P1, v2s(0.5f));
        v2f Phi2 = V2FMA(uc2, P2, v2s(0.5f));
        // pdf polys: e ~ exp(-s/2), quartic, clamped via s<=9
        v2f e1 = V2FMA(V2FMA(V2FMA(V2FMA(v2s(PB4), s1, v2s(PB3)), s1, v2s(PB2)),
                             s1, v2s(PB1)), s1, v2s(PB0));
        v2f e2 = V2FMA(V2FMA(V2FMA(V2FMA(v2s(PB4), s2, v2s(PB3)), s2, v2s(PB2)),
                             s2, v2s(PB1)), s2, v2s(PB0));
        v2f a  = V2FMA(mi, mj, v2s(Cm01[ii][jj]));
        v2f bb = V2FMA(v2s(Cqd[ii][jj]), mi, v2s(Cqj[ii][jj]) * mj);
        v2f cc = V2FMA(v2s(Cqi[ii][jj]), mi, v2s(Cqd[ii][jj]) * mj);
        v2f ta = V2FMA(a,  Phi1, bb * e1);
        v2f tb = V2FMA(cc, Phi1, v2s(Cc2[ii][jj]) * e1);
        v2f A  = acc[ii][jj];
        A = V2FMA(Phi2, ta, A);
        A = V2FMA(e2,   tb, A);
        A = V2FMA(-Ei,  Ej, A);
        acc[ii][jj] = A;
    };

#pragma unroll
    for (int q = 0; q < 3; ++q) {
        const int co = c0 + q * 4;
        float4 mi4[2], Ei4[2], mj4[2], Ej4[2];
#pragma unroll
        for (int r = 0; r < 2; ++r) {
            mi4[r] = *(const float4*)(smi + (ia + r) * RSTR + co);
            Ei4[r] = *(const float4*)(sEi + (ia + r) * RSTR + co);
            mj4[r] = *(const float4*)(smj + (jb + r) * RSTR + co);
            Ej4[r] = *(const float4*)(sEj + (jb + r) * RSTR + co);
        }
#pragma unroll
        for (int ii = 0; ii < 2; ++ii) {
#pragma unroll
            for (int jj = 0; jj < 2; ++jj) {
                v2f miL = {mi4[ii].x, mi4[ii].y}, miH = {mi4[ii].z, mi4[ii].w};
                v2f mjL = {mj4[jj].x, mj4[jj].y}, mjH = {mj4[jj].z, mj4[jj].w};
                v2f EiL = {Ei4[ii].x, Ei4[ii].y}, EiH = {Ei4[ii].z, Ei4[ii].w};
                v2f EjL = {Ej4[jj].x, Ej4[jj].y}, EjH = {Ej4[jj].z, Ej4[jj].w};
                elem2(ii, jj, miL, mjL, EiL, EjL);
                elem2(ii, jj, miH, mjH, EiH, EjH);
            }
        }
    }

#pragma unroll
    for (int ii = 0; ii < 2; ++ii)
#pragma unroll
        for (int jj = 0; jj < 2; ++jj)
            red[ch * 256 + (ia + ii) * 16 + (jb + jj)] =
                acc[ii][jj].x + acc[ii][jj].y;
    __syncthreads();

    if (tid < 256) {
        float sum = 0.0f;
#pragma unroll
        for (int k = 0; k < 8; ++k) sum += red[k * 256 + tid];
        const int i = ti * TT + (tid >> 4);
        const int j = tj * TT + (tid & 15);
        if (i < j) {
            float v = sum * (1.0f / 96.0f);
            out[COV_OFF + ((size_t)(b * NN + i)) * NN + j] = v;
            out[COV_OFF + ((size_t)(b * NN + j)) * NN + i] = v;
        }
    }
}

extern "C" void kernel_launch(void* const* d_in, const int* in_sizes, int n_in,
                              void* d_out, int out_size, void* d_ws, size_t ws_size,
                              hipStream_t stream) {
    const float* xin    = (const float*)d_in[0];
    const float* meanin = (const float*)d_in[1];
    const float* kin    = (const float*)d_in[2];
    float* out = (float*)d_out;

    relu_cov_fused<<<BSZ * NTILES, 512, 0, stream>>>(xin, meanin, kin, out);
}